// Round 7
// baseline (300.285 us; speedup 1.0000x reference)
//
#include <hip/hip_runtime.h>

// Inputs (setup_inputs order):
//  0: coords [100000*3] f32; 1-6: pair i/j/coul/a12/b6/b10 [8M];
//  7-12: pair14 i/j/coul/a12/b6/b10 [500K]
// Output: [4] f32 = [e_coul, e_lj, e_coul14, e_lj14]
//
// R6 post-mortem: MLP-from-source attempts null (compiler re-serializes;
// VGPR stayed ~52). Model: time = N_vmem x latency / outstanding_per_CU,
// outstanding capped ~160. R7 test: NON-TEMPORAL (no-allocate) gathers --
// gathers hit L1 at ~2% and thrash the 32KB TCP; if L1 allocation is the
// concurrency cap, NT gathers bypass it. Structure = exact R4 (92us best).

#define BLOCK 256
#define GRID  2048

typedef int   intx4   __attribute__((ext_vector_type(4)));
typedef float floatx4 __attribute__((ext_vector_type(4)));

__global__ void pack_coords_kernel(const float* __restrict__ coords,
                                   float4* __restrict__ packed, int natom) {
    int i = blockIdx.x * blockDim.x + threadIdx.x;
    if (i < natom) {
        packed[i] = make_float4(coords[3 * i + 0], coords[3 * i + 1],
                                coords[3 * i + 2], 0.0f);
    }
}

__device__ __forceinline__ void pair_math(floatx4 ci, floatx4 cj, float coul,
                                          float a12, float b6, float b10,
                                          double& ec, double& ev) {
    float dx = ci.x - cj.x;
    float dy = ci.y - cj.y;
    float dz = ci.z - cj.z;
    float r2 = dx * dx + dy * dy + dz * dz;
    float inv_r2 = 1.0f / r2;
    float inv_r  = sqrtf(inv_r2);
    float inv_r6 = inv_r2 * inv_r2 * inv_r2;
    ec += (double)(coul * inv_r);
    ev += (double)(a12 * inv_r6 * inv_r6 - b6 * inv_r6
                 - b10 * inv_r6 * inv_r2 * inv_r2);
}

// Non-temporal (no-allocate) gather of one packed coord.
__device__ __forceinline__ floatx4 gather_nt(const floatx4* __restrict__ packed,
                                             int idx) {
    return __builtin_nontemporal_load(packed + idx);
}

__device__ __forceinline__ void pair_term_packed(const floatx4* __restrict__ packed,
                                                 int i, int j, float coul, float a12,
                                                 float b6, float b10,
                                                 double& ec, double& ev) {
    pair_math(gather_nt(packed, i), gather_nt(packed, j), coul, a12, b6, b10, ec, ev);
}

__device__ __forceinline__ void pair_term_direct(const float* __restrict__ coords,
                                                 int i, int j, float coul, float a12,
                                                 float b6, float b10,
                                                 double& ec, double& ev) {
    int ia = i * 3, ja = j * 3;
    floatx4 ci, cj;
    ci.x = coords[ia]; ci.y = coords[ia + 1]; ci.z = coords[ia + 2]; ci.w = 0.f;
    cj.x = coords[ja]; cj.y = coords[ja + 1]; cj.z = coords[ja + 2]; cj.w = 0.f;
    pair_math(ci, cj, coul, a12, b6, b10, ec, ev);
}

__device__ __forceinline__ void scan_list(const float* __restrict__ coords,
                                          const floatx4* __restrict__ packed,
                                          const int* __restrict__ ii,
                                          const int* __restrict__ jj,
                                          const float* __restrict__ coul,
                                          const float* __restrict__ a12,
                                          const float* __restrict__ b6,
                                          const float* __restrict__ b10,
                                          int n, int tid, int nthreads,
                                          double& ec, double& ev) {
    int n4 = n >> 2;
    if (packed) {
        for (int c = tid; c < n4; c += nthreads) {
            intx4   i4 = __builtin_nontemporal_load(((const intx4*)ii) + c);
            intx4   j4 = __builtin_nontemporal_load(((const intx4*)jj) + c);
            floatx4 c4 = __builtin_nontemporal_load(((const floatx4*)coul) + c);
            floatx4 a4 = __builtin_nontemporal_load(((const floatx4*)a12) + c);
            floatx4 b4 = __builtin_nontemporal_load(((const floatx4*)b6) + c);
            floatx4 h4 = __builtin_nontemporal_load(((const floatx4*)b10) + c);
            pair_term_packed(packed, i4.x, j4.x, c4.x, a4.x, b4.x, h4.x, ec, ev);
            pair_term_packed(packed, i4.y, j4.y, c4.y, a4.y, b4.y, h4.y, ec, ev);
            pair_term_packed(packed, i4.z, j4.z, c4.z, a4.z, b4.z, h4.z, ec, ev);
            pair_term_packed(packed, i4.w, j4.w, c4.w, a4.w, b4.w, h4.w, ec, ev);
        }
        for (int p = (n4 << 2) + tid; p < n; p += nthreads) {
            pair_term_packed(packed, ii[p], jj[p], coul[p], a12[p], b6[p], b10[p], ec, ev);
        }
    } else {
        for (int c = tid; c < n4; c += nthreads) {
            intx4   i4 = ((const intx4*)ii)[c];
            intx4   j4 = ((const intx4*)jj)[c];
            floatx4 c4 = ((const floatx4*)coul)[c];
            floatx4 a4 = ((const floatx4*)a12)[c];
            floatx4 b4 = ((const floatx4*)b6)[c];
            floatx4 h4 = ((const floatx4*)b10)[c];
            pair_term_direct(coords, i4.x, j4.x, c4.x, a4.x, b4.x, h4.x, ec, ev);
            pair_term_direct(coords, i4.y, j4.y, c4.y, a4.y, b4.y, h4.y, ec, ev);
            pair_term_direct(coords, i4.z, j4.z, c4.z, a4.z, b4.z, h4.z, ec, ev);
            pair_term_direct(coords, i4.w, j4.w, c4.w, a4.w, b4.w, h4.w, ec, ev);
        }
        for (int p = (n4 << 2) + tid; p < n; p += nthreads) {
            pair_term_direct(coords, ii[p], jj[p], coul[p], a12[p], b6[p], b10[p], ec, ev);
        }
    }
}

__global__ __launch_bounds__(BLOCK) void fused_pair_kernel(
        const float* __restrict__ coords, const floatx4* __restrict__ packed,
        const int* __restrict__ p_i, const int* __restrict__ p_j,
        const float* __restrict__ p_coul, const float* __restrict__ p_a12,
        const float* __restrict__ p_b6, const float* __restrict__ p_b10, int n_pair,
        const int* __restrict__ q_i, const int* __restrict__ q_j,
        const float* __restrict__ q_coul, const float* __restrict__ q_a12,
        const float* __restrict__ q_b6, const float* __restrict__ q_b10, int n_pair14,
        double* __restrict__ partials) {
    double ec = 0.0, ev = 0.0, ec14 = 0.0, ev14 = 0.0;
    int tid = blockIdx.x * blockDim.x + threadIdx.x;
    int nthreads = gridDim.x * blockDim.x;

    scan_list(coords, packed, p_i, p_j, p_coul, p_a12, p_b6, p_b10, n_pair,
              tid, nthreads, ec, ev);
    scan_list(coords, packed, q_i, q_j, q_coul, q_a12, q_b6, q_b10, n_pair14,
              tid, nthreads, ec14, ev14);

    for (int off = 32; off > 0; off >>= 1) {
        ec   += __shfl_down(ec,   off, 64);
        ev   += __shfl_down(ev,   off, 64);
        ec14 += __shfl_down(ec14, off, 64);
        ev14 += __shfl_down(ev14, off, 64);
    }

    __shared__ double s[BLOCK / 64][4];
    int lane = threadIdx.x & 63;
    int wid  = threadIdx.x >> 6;
    if (lane == 0) { s[wid][0] = ec; s[wid][1] = ev; s[wid][2] = ec14; s[wid][3] = ev14; }
    __syncthreads();

    if (threadIdx.x == 0) {
        double t0 = 0, t1 = 0, t2 = 0, t3 = 0;
        for (int w = 0; w < BLOCK / 64; ++w) {
            t0 += s[w][0]; t1 += s[w][1]; t2 += s[w][2]; t3 += s[w][3];
        }
        double* row = partials + (size_t)blockIdx.x * 4;
        row[0] = t0; row[1] = t1; row[2] = t2; row[3] = t3;
    }
}

__global__ __launch_bounds__(BLOCK) void finalize_kernel(
        const double* __restrict__ partials, int nrows,
        float* __restrict__ out) {
    double acc0 = 0, acc1 = 0, acc2 = 0, acc3 = 0;
    for (int r = threadIdx.x; r < nrows; r += blockDim.x) {
        const double* row = partials + (size_t)r * 4;
        acc0 += row[0]; acc1 += row[1]; acc2 += row[2]; acc3 += row[3];
    }
    for (int off = 32; off > 0; off >>= 1) {
        acc0 += __shfl_down(acc0, off, 64);
        acc1 += __shfl_down(acc1, off, 64);
        acc2 += __shfl_down(acc2, off, 64);
        acc3 += __shfl_down(acc3, off, 64);
    }
    __shared__ double s[BLOCK / 64][4];
    int lane = threadIdx.x & 63;
    int wid  = threadIdx.x >> 6;
    if (lane == 0) { s[wid][0] = acc0; s[wid][1] = acc1; s[wid][2] = acc2; s[wid][3] = acc3; }
    __syncthreads();
    if (threadIdx.x == 0) {
        double t0 = 0, t1 = 0, t2 = 0, t3 = 0;
        for (int w = 0; w < BLOCK / 64; ++w) {
            t0 += s[w][0]; t1 += s[w][1]; t2 += s[w][2]; t3 += s[w][3];
        }
        out[0] = (float)t0; out[1] = (float)t1;
        out[2] = (float)t2; out[3] = (float)t3;
    }
}

extern "C" void kernel_launch(void* const* d_in, const int* in_sizes, int n_in,
                              void* d_out, int out_size, void* d_ws, size_t ws_size,
                              hipStream_t stream) {
    const float* coords = (const float*)d_in[0];
    int natom = in_sizes[0] / 3;

    const int*   p_i    = (const int*)d_in[1];
    const int*   p_j    = (const int*)d_in[2];
    const float* p_coul = (const float*)d_in[3];
    const float* p_a12  = (const float*)d_in[4];
    const float* p_b6   = (const float*)d_in[5];
    const float* p_b10  = (const float*)d_in[6];
    int n_pair = in_sizes[1];

    const int*   q_i    = (const int*)d_in[7];
    const int*   q_j    = (const int*)d_in[8];
    const float* q_coul = (const float*)d_in[9];
    const float* q_a12  = (const float*)d_in[10];
    const float* q_b6   = (const float*)d_in[11];
    const float* q_b10  = (const float*)d_in[12];
    int n_pair14 = in_sizes[7];

    float* out = (float*)d_out;

    // d_ws layout: [packed coords: natom*16B] [partials: GRID*32B]
    size_t packed_bytes = (size_t)natom * sizeof(float4);
    size_t need = packed_bytes + (size_t)GRID * 4 * sizeof(double);

    floatx4* packed  = nullptr;
    double* partials = (double*)d_ws;
    int blocks = GRID;

    if (ws_size >= need) {
        packed   = (floatx4*)d_ws;
        partials = (double*)((char*)d_ws + packed_bytes);
        hipLaunchKernelGGL(pack_coords_kernel,
                           dim3((natom + BLOCK - 1) / BLOCK), dim3(BLOCK), 0, stream,
                           coords, (float4*)packed, natom);
    } else {
        size_t max_blocks = ws_size / (4 * sizeof(double));
        if ((size_t)blocks > max_blocks) blocks = (int)max_blocks;
        if (blocks < 1) blocks = 1;
    }

    hipLaunchKernelGGL(fused_pair_kernel, dim3(blocks), dim3(BLOCK), 0, stream,
                       coords, packed,
                       p_i, p_j, p_coul, p_a12, p_b6, p_b10, n_pair,
                       q_i, q_j, q_coul, q_a12, q_b6, q_b10, n_pair14,
                       partials);

    hipLaunchKernelGGL(finalize_kernel, dim3(1), dim3(BLOCK), 0, stream,
                       partials, blocks, out);
}

// Round 8
// 266.574 us; speedup vs baseline: 1.1265x; 1.1265x over previous
//
#include <hip/hip_runtime.h>

// Inputs (setup_inputs order):
//  0: coords [100000*3] f32; 1-6: pair i/j/coul/a12/b6/b10 [8M];
//  7-12: pair14 i/j/coul/a12/b6/b10 [500K]
// Output: [4] f32 = [e_coul, e_lj, e_coul14, e_lj14]
//
// R7 post-mortem: NT gathers bypass L2/L3 retention too -> +12MB HBM fetch,
// 129us (regression). R8: L1-bypass ONLY via inline-asm `sc0` gathers
// (device-scope load: skips TCP allocate/fill, keeps L2/L3 policy).
// Progressive vmcnt(6/4/2/0) fences; counts only my own younger loads so
// compiler-inserted stream loads can only make fences stricter (safe).
// Structure otherwise identical to R4 (92us best): NT streams, 4 pairs/thread.

#define BLOCK 256
#define GRID  2048

typedef int   intx4   __attribute__((ext_vector_type(4)));
typedef float floatx4 __attribute__((ext_vector_type(4)));

// Issue a 16B gather with sc0 (L1-bypass, L2-temporal). Result NOT ready
// until a following FENCE_PAIR.
#define GATHER_SC0(dst, addrexpr) \
    asm volatile("global_load_dwordx4 %0, %1, off sc0" \
                 : "=v"(dst) : "v"(addrexpr))

// Wait until at most N vmem ops outstanding; ties a,b so uses can't hoist.
#define FENCE_PAIR(a, b, N) \
    asm volatile("s_waitcnt vmcnt(" #N ")" : "+v"(a), "+v"(b))

__global__ void pack_coords_kernel(const float* __restrict__ coords,
                                   float4* __restrict__ packed, int natom) {
    int i = blockIdx.x * blockDim.x + threadIdx.x;
    if (i < natom) {
        packed[i] = make_float4(coords[3 * i + 0], coords[3 * i + 1],
                                coords[3 * i + 2], 0.0f);
    }
}

__device__ __forceinline__ void pair_math(floatx4 ci, floatx4 cj, float coul,
                                          float a12, float b6, float b10,
                                          double& ec, double& ev) {
    float dx = ci.x - cj.x;
    float dy = ci.y - cj.y;
    float dz = ci.z - cj.z;
    float r2 = dx * dx + dy * dy + dz * dz;
    float inv_r2 = 1.0f / r2;
    float inv_r  = sqrtf(inv_r2);
    float inv_r6 = inv_r2 * inv_r2 * inv_r2;
    ec += (double)(coul * inv_r);
    ev += (double)(a12 * inv_r6 * inv_r6 - b6 * inv_r6
                 - b10 * inv_r6 * inv_r2 * inv_r2);
}

__device__ __forceinline__ void pair_term_packed(const floatx4* __restrict__ packed,
                                                 int i, int j, float coul, float a12,
                                                 float b6, float b10,
                                                 double& ec, double& ev) {
    pair_math(packed[i], packed[j], coul, a12, b6, b10, ec, ev);
}

__device__ __forceinline__ void pair_term_direct(const float* __restrict__ coords,
                                                 int i, int j, float coul, float a12,
                                                 float b6, float b10,
                                                 double& ec, double& ev) {
    int ia = i * 3, ja = j * 3;
    floatx4 ci, cj;
    ci.x = coords[ia]; ci.y = coords[ia + 1]; ci.z = coords[ia + 2]; ci.w = 0.f;
    cj.x = coords[ja]; cj.y = coords[ja + 1]; cj.z = coords[ja + 2]; cj.w = 0.f;
    pair_math(ci, cj, coul, a12, b6, b10, ec, ev);
}

__device__ __forceinline__ void scan_list(const float* __restrict__ coords,
                                          const floatx4* __restrict__ packed,
                                          const int* __restrict__ ii,
                                          const int* __restrict__ jj,
                                          const float* __restrict__ coul,
                                          const float* __restrict__ a12,
                                          const float* __restrict__ b6,
                                          const float* __restrict__ b10,
                                          int n, int tid, int nthreads,
                                          double& ec, double& ev) {
    int n4 = n >> 2;
    if (packed) {
        for (int c = tid; c < n4; c += nthreads) {
            intx4 i4 = __builtin_nontemporal_load(((const intx4*)ii) + c);
            intx4 j4 = __builtin_nontemporal_load(((const intx4*)jj) + c);

            // 8 sc0 gathers issued oldest->newest: A0,P0,A1,P1,A2,P2,A3,P3
            floatx4 A0, A1, A2, A3, P0, P1, P2, P3;
            GATHER_SC0(A0, packed + i4.x); GATHER_SC0(P0, packed + j4.x);
            GATHER_SC0(A1, packed + i4.y); GATHER_SC0(P1, packed + j4.y);
            GATHER_SC0(A2, packed + i4.z); GATHER_SC0(P2, packed + j4.z);
            GATHER_SC0(A3, packed + i4.w); GATHER_SC0(P3, packed + j4.w);

            // Streams overlap with gathers (compiler-tracked waits).
            floatx4 c4 = __builtin_nontemporal_load(((const floatx4*)coul) + c);
            floatx4 a4 = __builtin_nontemporal_load(((const floatx4*)a12) + c);
            floatx4 b4 = __builtin_nontemporal_load(((const floatx4*)b6)  + c);
            floatx4 h4 = __builtin_nontemporal_load(((const floatx4*)b10) + c);

            FENCE_PAIR(A0, P0, 6);
            pair_math(A0, P0, c4.x, a4.x, b4.x, h4.x, ec, ev);
            FENCE_PAIR(A1, P1, 4);
            pair_math(A1, P1, c4.y, a4.y, b4.y, h4.y, ec, ev);
            FENCE_PAIR(A2, P2, 2);
            pair_math(A2, P2, c4.z, a4.z, b4.z, h4.z, ec, ev);
            FENCE_PAIR(A3, P3, 0);
            pair_math(A3, P3, c4.w, a4.w, b4.w, h4.w, ec, ev);
        }
        for (int p = (n4 << 2) + tid; p < n; p += nthreads) {
            pair_term_packed(packed, ii[p], jj[p], coul[p], a12[p], b6[p], b10[p], ec, ev);
        }
    } else {
        for (int c = tid; c < n4; c += nthreads) {
            intx4   i4 = ((const intx4*)ii)[c];
            intx4   j4 = ((const intx4*)jj)[c];
            floatx4 c4 = ((const floatx4*)coul)[c];
            floatx4 a4 = ((const floatx4*)a12)[c];
            floatx4 b4 = ((const floatx4*)b6)[c];
            floatx4 h4 = ((const floatx4*)b10)[c];
            pair_term_direct(coords, i4.x, j4.x, c4.x, a4.x, b4.x, h4.x, ec, ev);
            pair_term_direct(coords, i4.y, j4.y, c4.y, a4.y, b4.y, h4.y, ec, ev);
            pair_term_direct(coords, i4.z, j4.z, c4.z, a4.z, b4.z, h4.z, ec, ev);
            pair_term_direct(coords, i4.w, j4.w, c4.w, a4.w, b4.w, h4.w, ec, ev);
        }
        for (int p = (n4 << 2) + tid; p < n; p += nthreads) {
            pair_term_direct(coords, ii[p], jj[p], coul[p], a12[p], b6[p], b10[p], ec, ev);
        }
    }
}

__global__ __launch_bounds__(BLOCK) void fused_pair_kernel(
        const float* __restrict__ coords, const floatx4* __restrict__ packed,
        const int* __restrict__ p_i, const int* __restrict__ p_j,
        const float* __restrict__ p_coul, const float* __restrict__ p_a12,
        const float* __restrict__ p_b6, const float* __restrict__ p_b10, int n_pair,
        const int* __restrict__ q_i, const int* __restrict__ q_j,
        const float* __restrict__ q_coul, const float* __restrict__ q_a12,
        const float* __restrict__ q_b6, const float* __restrict__ q_b10, int n_pair14,
        double* __restrict__ partials) {
    double ec = 0.0, ev = 0.0, ec14 = 0.0, ev14 = 0.0;
    int tid = blockIdx.x * blockDim.x + threadIdx.x;
    int nthreads = gridDim.x * blockDim.x;

    scan_list(coords, packed, p_i, p_j, p_coul, p_a12, p_b6, p_b10, n_pair,
              tid, nthreads, ec, ev);
    scan_list(coords, packed, q_i, q_j, q_coul, q_a12, q_b6, q_b10, n_pair14,
              tid, nthreads, ec14, ev14);

    for (int off = 32; off > 0; off >>= 1) {
        ec   += __shfl_down(ec,   off, 64);
        ev   += __shfl_down(ev,   off, 64);
        ec14 += __shfl_down(ec14, off, 64);
        ev14 += __shfl_down(ev14, off, 64);
    }

    __shared__ double s[BLOCK / 64][4];
    int lane = threadIdx.x & 63;
    int wid  = threadIdx.x >> 6;
    if (lane == 0) { s[wid][0] = ec; s[wid][1] = ev; s[wid][2] = ec14; s[wid][3] = ev14; }
    __syncthreads();

    if (threadIdx.x == 0) {
        double t0 = 0, t1 = 0, t2 = 0, t3 = 0;
        for (int w = 0; w < BLOCK / 64; ++w) {
            t0 += s[w][0]; t1 += s[w][1]; t2 += s[w][2]; t3 += s[w][3];
        }
        double* row = partials + (size_t)blockIdx.x * 4;
        row[0] = t0; row[1] = t1; row[2] = t2; row[3] = t3;
    }
}

__global__ __launch_bounds__(BLOCK) void finalize_kernel(
        const double* __restrict__ partials, int nrows,
        float* __restrict__ out) {
    double acc0 = 0, acc1 = 0, acc2 = 0, acc3 = 0;
    for (int r = threadIdx.x; r < nrows; r += blockDim.x) {
        const double* row = partials + (size_t)r * 4;
        acc0 += row[0]; acc1 += row[1]; acc2 += row[2]; acc3 += row[3];
    }
    for (int off = 32; off > 0; off >>= 1) {
        acc0 += __shfl_down(acc0, off, 64);
        acc1 += __shfl_down(acc1, off, 64);
        acc2 += __shfl_down(acc2, off, 64);
        acc3 += __shfl_down(acc3, off, 64);
    }
    __shared__ double s[BLOCK / 64][4];
    int lane = threadIdx.x & 63;
    int wid  = threadIdx.x >> 6;
    if (lane == 0) { s[wid][0] = acc0; s[wid][1] = acc1; s[wid][2] = acc2; s[wid][3] = acc3; }
    __syncthreads();
    if (threadIdx.x == 0) {
        double t0 = 0, t1 = 0, t2 = 0, t3 = 0;
        for (int w = 0; w < BLOCK / 64; ++w) {
            t0 += s[w][0]; t1 += s[w][1]; t2 += s[w][2]; t3 += s[w][3];
        }
        out[0] = (float)t0; out[1] = (float)t1;
        out[2] = (float)t2; out[3] = (float)t3;
    }
}

extern "C" void kernel_launch(void* const* d_in, const int* in_sizes, int n_in,
                              void* d_out, int out_size, void* d_ws, size_t ws_size,
                              hipStream_t stream) {
    const float* coords = (const float*)d_in[0];
    int natom = in_sizes[0] / 3;

    const int*   p_i    = (const int*)d_in[1];
    const int*   p_j    = (const int*)d_in[2];
    const float* p_coul = (const float*)d_in[3];
    const float* p_a12  = (const float*)d_in[4];
    const float* p_b6   = (const float*)d_in[5];
    const float* p_b10  = (const float*)d_in[6];
    int n_pair = in_sizes[1];

    const int*   q_i    = (const int*)d_in[7];
    const int*   q_j    = (const int*)d_in[8];
    const float* q_coul = (const float*)d_in[9];
    const float* q_a12  = (const float*)d_in[10];
    const float* q_b6   = (const float*)d_in[11];
    const float* q_b10  = (const float*)d_in[12];
    int n_pair14 = in_sizes[7];

    float* out = (float*)d_out;

    // d_ws layout: [packed coords: natom*16B] [partials: GRID*32B]
    size_t packed_bytes = (size_t)natom * sizeof(float4);
    size_t need = packed_bytes + (size_t)GRID * 4 * sizeof(double);

    floatx4* packed  = nullptr;
    double* partials = (double*)d_ws;
    int blocks = GRID;

    if (ws_size >= need) {
        packed   = (floatx4*)d_ws;
        partials = (double*)((char*)d_ws + packed_bytes);
        hipLaunchKernelGGL(pack_coords_kernel,
                           dim3((natom + BLOCK - 1) / BLOCK), dim3(BLOCK), 0, stream,
                           coords, (float4*)packed, natom);
    } else {
        size_t max_blocks = ws_size / (4 * sizeof(double));
        if ((size_t)blocks > max_blocks) blocks = (int)max_blocks;
        if (blocks < 1) blocks = 1;
    }

    hipLaunchKernelGGL(fused_pair_kernel, dim3(blocks), dim3(BLOCK), 0, stream,
                       coords, packed,
                       p_i, p_j, p_coul, p_a12, p_b6, p_b10, n_pair,
                       q_i, q_j, q_coul, q_a12, q_b6, q_b10, n_pair14,
                       partials);

    hipLaunchKernelGGL(finalize_kernel, dim3(1), dim3(BLOCK), 0, stream,
                       partials, blocks, out);
}